// Round 3
// baseline (3660.278 us; speedup 1.0000x reference)
//
#include <hip/hip_runtime.h>

#define N_NODES 10000
#define B 8
#define T_STEPS 12
#define E_EDGES 160000
#define HG 64
#define HR 64
#define P_OUT 12
#define BN (B * N_NODES)   // 80000

// ---------------- GCN normalization + aggregation ----------------

__global__ void deg_kernel(const int* __restrict__ ei, const float* __restrict__ ew,
                           float* __restrict__ deg) {
    int e = blockIdx.x * blockDim.x + threadIdx.x;
    if (e < E_EDGES) atomicAdd(&deg[ei[E_EDGES + e]], ew[e]);
}

__global__ void dinv_kernel(float* __restrict__ deg) {
    int n = blockIdx.x * blockDim.x + threadIdx.x;
    if (n < N_NODES) deg[n] = rsqrtf(deg[n] + 1.0f);   // +1 = self-loop weight
}

// Self-loop contribution: aggS[t*BN + b*N + n] = dinv[n]^2 * x[b,n,t]
__global__ void self_kernel(const float* __restrict__ x, const float* __restrict__ dinv,
                            float* __restrict__ aggS) {
    int tid = blockIdx.x * blockDim.x + threadIdx.x;
    if (tid >= BN * T_STEPS) return;
    int n = tid % N_NODES;
    int b = (tid / N_NODES) % B;
    int t = tid / BN;
    float di = dinv[n];
    aggS[tid] = di * di * x[(b * N_NODES + n) * T_STEPS + t];
}

// Edge contribution: one thread per (edge, b); 12 atomics (one per t)
__global__ void edge_kernel(const int* __restrict__ ei, const float* __restrict__ ew,
                            const float* __restrict__ dinv, const float* __restrict__ x,
                            float* __restrict__ aggS) {
    int tid = blockIdx.x * blockDim.x + threadIdx.x;
    if (tid >= E_EDGES * B) return;
    int e = tid % E_EDGES;
    int b = tid / E_EDGES;
    int s = ei[e];
    int d = ei[E_EDGES + e];
    float norm = dinv[s] * ew[e] * dinv[d];
    // (b*N+s)*12 floats = 48B offset -> 16B aligned, safe for float4
    const float4* xp = reinterpret_cast<const float4*>(&x[(b * N_NODES + s) * T_STEPS]);
    float4 x0 = xp[0], x1 = xp[1], x2 = xp[2];
    float* dst = &aggS[b * N_NODES + d];
    atomicAdd(dst + 0 * BN,  norm * x0.x);
    atomicAdd(dst + 1 * BN,  norm * x0.y);
    atomicAdd(dst + 2 * BN,  norm * x0.z);
    atomicAdd(dst + 3 * BN,  norm * x0.w);
    atomicAdd(dst + 4 * BN,  norm * x1.x);
    atomicAdd(dst + 5 * BN,  norm * x1.y);
    atomicAdd(dst + 6 * BN,  norm * x1.z);
    atomicAdd(dst + 7 * BN,  norm * x1.w);
    atomicAdd(dst + 8 * BN,  norm * x2.x);
    atomicAdd(dst + 9 * BN,  norm * x2.y);
    atomicAdd(dst + 10 * BN, norm * x2.z);
    atomicAdd(dst + 11 * BN, norm * x2.w);
}

// ---------------- Fused GRU + output head ----------------

__device__ __forceinline__ float fast_rcp(float v) { return __builtin_amdgcn_rcpf(v); }
__device__ __forceinline__ float sigmoid_f(float v) { return fast_rcp(1.0f + __expf(-v)); }
__device__ __forceinline__ float tanh_f(float v) {
    // 2/(1+exp(-2v)) - 1 ; exp overflow -> rcp(inf)=0 -> -1, correct saturation
    float e = __expf(-2.0f * v);
    return fmaf(2.0f, fast_rcp(1.0f + e), -1.0f);
}

// 4 threads per sequence (jq = tid>>6 picks 16 of 64 GRU units), 64 sequences
// per 256-thread block -> 4 waves/block, 5000 waves total (vs 1250 before):
// occupancy was the R2 bottleneck (1.2 waves/SIMD, VALUBusy 31%).
// h_sh[j][seq]: lane==seq -> stride-1, 2 lanes/bank (free). Each thread keeps
// a full h[64] + xt[64] copy in regs with static indexing only; the one
// dynamic-indexed value (h_prev[j]) reads the thread's own LDS cell, which is
// written by no other thread and is barrier-separated from cross-thread reads.
__global__ __launch_bounds__(256) void gru_kernel(
    const float* __restrict__ aggS,
    const float* __restrict__ gW, const float* __restrict__ gb,
    const float* __restrict__ Wih, const float* __restrict__ Whh,
    const float* __restrict__ bih, const float* __restrict__ bhh,
    const float* __restrict__ Wout, const float* __restrict__ bout,
    float* __restrict__ out)
{
    __shared__ float h_sh[64 * 64];   // [j][seq], 16 KB
    const int tid = threadIdx.x;
    const int seq = tid & 63;
    const int jq  = tid >> 6;        // wave-uniform
    const int j0  = jq * 16;
    const int bn  = blockIdx.x * 64 + seq;   // BN = 1250*64 exactly

    float h[64];
#pragma unroll
    for (int k = 0; k < 64; k++) h[k] = 0.0f;
#pragma unroll
    for (int jj = 0; jj < 16; jj++) h_sh[(j0 + jj) * 64 + seq] = 0.0f;
    __syncthreads();

#pragma unroll 1
    for (int t = 0; t < T_STEPS; t++) {
        const float a = aggS[t * BN + bn];
        float xt[64];
#pragma unroll
        for (int k = 0; k < 64; k++) xt[k] = fmaxf(fmaf(a, gW[k], gb[k]), 0.0f);

#pragma unroll 1
        for (int jj = 0; jj < 16; jj++) {
            const int j = j0 + jj;
            float air = bih[j], aiz = bih[j + 64], ain = bih[j + 128];
            float ahr = bhh[j], ahz = bhh[j + 64], ahn = bhh[j + 128];
            const float* wr = &Wih[j * 64];
            const float* wz = &Wih[(j + 64) * 64];
            const float* wn = &Wih[(j + 128) * 64];
            const float* vr = &Whh[j * 64];
            const float* vz = &Whh[(j + 64) * 64];
            const float* vn = &Whh[(j + 128) * 64];
#pragma unroll
            for (int k = 0; k < 64; k++) {
                const float xk = xt[k], hk = h[k];
                air = fmaf(wr[k], xk, air);
                aiz = fmaf(wz[k], xk, aiz);
                ain = fmaf(wn[k], xk, ain);
                ahr = fmaf(vr[k], hk, ahr);
                ahz = fmaf(vz[k], hk, ahz);
                ahn = fmaf(vn[k], hk, ahn);
            }
            float r = sigmoid_f(air + ahr);
            float z = sigmoid_f(aiz + ahz);
            float nn = tanh_f(fmaf(r, ahn, ain));
            float hp = h_sh[j * 64 + seq];   // own cell: still h_{t-1}[j]
            h_sh[j * 64 + seq] = (1.0f - z) * nn + z * hp;
        }
        __syncthreads();                     // all 64 h_t values written
#pragma unroll
        for (int k = 0; k < 64; k++) h[k] = h_sh[k * 64 + seq];
        __syncthreads();                     // reads done before next-t writes
    }

    // output head: 3 outputs per thread (4*3 = 12 = P_OUT)
#pragma unroll 1
    for (int pp = 0; pp < 3; pp++) {
        const int p = jq * 3 + pp;
        float acc = bout[p];
#pragma unroll
        for (int k = 0; k < 64; k++) acc = fmaf(Wout[p * 64 + k], h[k], acc);
        out[(long)bn * P_OUT + p] = acc;
    }
}

// ---------------- launcher ----------------

extern "C" void kernel_launch(void* const* d_in, const int* in_sizes, int n_in,
                              void* d_out, int out_size, void* d_ws, size_t ws_size,
                              hipStream_t stream)
{
    const float* x    = (const float*)d_in[0];
    const int*   ei   = (const int*)  d_in[1];
    const float* ew   = (const float*)d_in[2];
    const float* gW   = (const float*)d_in[3];
    const float* gb   = (const float*)d_in[4];
    const float* Wih  = (const float*)d_in[5];
    const float* Whh  = (const float*)d_in[6];
    const float* bih  = (const float*)d_in[7];
    const float* bhh  = (const float*)d_in[8];
    const float* Wout = (const float*)d_in[9];
    const float* bout = (const float*)d_in[10];
    float* out = (float*)d_out;

    float* deg  = (float*)d_ws;          // N floats (becomes dinv in-place)
    float* aggS = deg + N_NODES;         // BN*T floats

    hipMemsetAsync(deg, 0, N_NODES * sizeof(float), stream);
    deg_kernel<<<(E_EDGES + 255) / 256, 256, 0, stream>>>(ei, ew, deg);
    dinv_kernel<<<(N_NODES + 255) / 256, 256, 0, stream>>>(deg);
    self_kernel<<<(BN * T_STEPS + 255) / 256, 256, 0, stream>>>(x, deg, aggS);
    edge_kernel<<<(E_EDGES * B + 255) / 256, 256, 0, stream>>>(ei, ew, deg, x, aggS);
    gru_kernel<<<BN / 64, 256, 0, stream>>>(aggS, gW, gb, Wih, Whh, bih, bhh,
                                            Wout, bout, out);
}

// Round 4
// 962.431 us; speedup vs baseline: 3.8032x; 3.8032x over previous
//
#include <hip/hip_runtime.h>

#define N_NODES 10000
#define B 8
#define T_STEPS 12
#define E_EDGES 160000
#define HG 64
#define HR 64
#define P_OUT 12
#define BN (B * N_NODES)   // 80000

typedef __attribute__((ext_vector_type(8))) short short8;
typedef __attribute__((ext_vector_type(4))) float f32x4;

__device__ __forceinline__ short f2bf(float f) {
    unsigned u = __builtin_bit_cast(unsigned, f);
    u += 0x7FFFu + ((u >> 16) & 1u);     // round-to-nearest-even
    return (short)(u >> 16);
}

// ---------------- GCN normalization + aggregation ----------------

__global__ void deg_kernel(const int* __restrict__ ei, const float* __restrict__ ew,
                           float* __restrict__ deg) {
    int e = blockIdx.x * blockDim.x + threadIdx.x;
    if (e < E_EDGES) atomicAdd(&deg[ei[E_EDGES + e]], ew[e]);
}

__global__ void dinv_kernel(float* __restrict__ deg) {
    int n = blockIdx.x * blockDim.x + threadIdx.x;
    if (n < N_NODES) deg[n] = rsqrtf(deg[n] + 1.0f);   // +1 = self-loop weight
}

__global__ void self_kernel(const float* __restrict__ x, const float* __restrict__ dinv,
                            float* __restrict__ aggS) {
    int tid = blockIdx.x * blockDim.x + threadIdx.x;
    if (tid >= BN * T_STEPS) return;
    int n = tid % N_NODES;
    int b = (tid / N_NODES) % B;
    int t = tid / BN;
    float di = dinv[n];
    aggS[tid] = di * di * x[(b * N_NODES + n) * T_STEPS + t];
}

__global__ void edge_kernel(const int* __restrict__ ei, const float* __restrict__ ew,
                            const float* __restrict__ dinv, const float* __restrict__ x,
                            float* __restrict__ aggS) {
    int tid = blockIdx.x * blockDim.x + threadIdx.x;
    if (tid >= E_EDGES * B) return;
    int e = tid % E_EDGES;
    int b = tid / E_EDGES;
    int s = ei[e];
    int d = ei[E_EDGES + e];
    float norm = dinv[s] * ew[e] * dinv[d];
    const float4* xp = reinterpret_cast<const float4*>(&x[(b * N_NODES + s) * T_STEPS]);
    float4 x0 = xp[0], x1 = xp[1], x2 = xp[2];
    float* dst = &aggS[b * N_NODES + d];
    atomicAdd(dst + 0 * BN,  norm * x0.x);
    atomicAdd(dst + 1 * BN,  norm * x0.y);
    atomicAdd(dst + 2 * BN,  norm * x0.z);
    atomicAdd(dst + 3 * BN,  norm * x0.w);
    atomicAdd(dst + 4 * BN,  norm * x1.x);
    atomicAdd(dst + 5 * BN,  norm * x1.y);
    atomicAdd(dst + 6 * BN,  norm * x1.z);
    atomicAdd(dst + 7 * BN,  norm * x1.w);
    atomicAdd(dst + 8 * BN,  norm * x2.x);
    atomicAdd(dst + 9 * BN,  norm * x2.y);
    atomicAdd(dst + 10 * BN, norm * x2.z);
    atomicAdd(dst + 11 * BN, norm * x2.w);
}

// ---------------- weight conversion to bf16 ----------------
// Wihb/Whhb: [192][64] bf16 row-major; Woutb: [16][64] bf16 (rows 12..15 zero)

__global__ void cvt_kernel(const float* __restrict__ Wih, const float* __restrict__ Whh,
                           const float* __restrict__ Wout,
                           short* __restrict__ Wihb, short* __restrict__ Whhb,
                           short* __restrict__ Woutb) {
    int i = blockIdx.x * blockDim.x + threadIdx.x;
    if (i < 192 * 64) {
        Wihb[i] = f2bf(Wih[i]);
        Whhb[i] = f2bf(Whh[i]);
    }
    if (i < 16 * 64) {
        int p = i >> 6, k = i & 63;
        Woutb[i] = (p < P_OUT) ? f2bf(Wout[p * 64 + k]) : (short)0;
    }
}

// ---------------- Fused MFMA GRU + output head ----------------

__device__ __forceinline__ float fast_rcp(float v) { return __builtin_amdgcn_rcpf(v); }
__device__ __forceinline__ float sigmoid_f(float v) { return fast_rcp(1.0f + __expf(-v)); }
__device__ __forceinline__ float tanh_f(float v) {
    float e = __expf(-2.0f * v);
    return fmaf(2.0f, fast_rcp(1.0f + e), -1.0f);
}

// Block = 64 sequences, 4 waves. Wave w owns gate-units u in [16w,16w+16).
// Per t: gates(64 seq x 192) = X(64x64)*Wih^T + H(64x64)*Whh^T via
// mfma_f32_16x16x32_bf16. Four acc sets (r,z,n_x,n_h) at identical tile
// coords -> all four pre-activations for a (seq,u) sit in the same lane&reg:
// elementwise needs NO cross-wave exchange. h kept fp32 in C-layout regs
// (recurrence precision) + bf16 XOR-swizzled LDS copy for next-t A-frags.
// Weights live in B-frag registers for the whole kernel (48 VGPR) -- kills
// the R2/R3 weight-reload bottleneck.
// Layouts (guide §3, m89/m91-verified): A[m=lane&15][k=(lane>>4)*8+j],
// B[n=lane&15][k=(lane>>4)*8+j] (B^T rows), D: col=lane&15, row=(lane>>4)*4+reg.
__global__ __launch_bounds__(256, 2) void gru_mfma_kernel(
    const float* __restrict__ aggS,
    const float* __restrict__ gW, const float* __restrict__ gb,
    const short* __restrict__ Wihb, const short* __restrict__ Whhb,
    const float* __restrict__ bih, const float* __restrict__ bhh,
    const short* __restrict__ Woutb, const float* __restrict__ bout,
    float* __restrict__ out)
{
    __shared__ short hlds[64 * 64];   // 8 KB, row=seq, 8 chunks of 8 bf16, chunk XOR (seq&7)
    const int tid = threadIdx.x;
    const int w   = tid >> 6;         // wave id (wave-uniform)
    const int l   = tid & 63;
    const int lr  = l & 15;
    const int qu  = l >> 4;
    const int blk = blockIdx.x;

    // ---- t-invariant preloads ----
    short8 bIr[2], bIz[2], bIn[2], bHr[2], bHz[2], bHn[2];
#pragma unroll
    for (int kt = 0; kt < 2; kt++) {
        const int ko = kt * 32 + qu * 8;
        bIr[kt] = *(const short8*)&Wihb[(      16 * w + lr) * 64 + ko];
        bIz[kt] = *(const short8*)&Wihb[( 64 + 16 * w + lr) * 64 + ko];
        bIn[kt] = *(const short8*)&Wihb[(128 + 16 * w + lr) * 64 + ko];
        bHr[kt] = *(const short8*)&Whhb[(      16 * w + lr) * 64 + ko];
        bHz[kt] = *(const short8*)&Whhb[( 64 + 16 * w + lr) * 64 + ko];
        bHn[kt] = *(const short8*)&Whhb[(128 + 16 * w + lr) * 64 + ko];
    }
    float gw8[2][8], gb8[2][8];
#pragma unroll
    for (int kt = 0; kt < 2; kt++) {
        const int ko = kt * 32 + qu * 8;
#pragma unroll
        for (int j = 0; j < 8; j++) { gw8[kt][j] = gW[ko + j]; gb8[kt][j] = gb[ko + j]; }
    }
    const int u = 16 * w + lr;        // this lane's gate-unit
    const float bR  = bih[u]       + bhh[u];
    const float bZ  = bih[u + 64]  + bhh[u + 64];
    const float bIN = bih[u + 128];
    const float bHN = bhh[u + 128];
    const int uc = u >> 3;            // write-swizzle chunk base
    const int u7 = u & 7;

    float h_c[4][4];
#pragma unroll
    for (int mt = 0; mt < 4; mt++)
#pragma unroll
        for (int r = 0; r < 4; r++) h_c[mt][r] = 0.0f;
#pragma unroll
    for (int i = 0; i < 16; i++) hlds[tid * 16 + i] = 0;
    __syncthreads();

#pragma unroll 1
    for (int t = 0; t < T_STEPS; t++) {
        float a_[4];
#pragma unroll
        for (int mt = 0; mt < 4; mt++)
            a_[mt] = aggS[t * BN + blk * 64 + mt * 16 + lr];

        f32x4 accR[4], accZ[4], accNX[4], accNH[4];
#pragma unroll
        for (int mt = 0; mt < 4; mt++) {
            accR[mt]  = (f32x4){0.f, 0.f, 0.f, 0.f};
            accZ[mt]  = (f32x4){0.f, 0.f, 0.f, 0.f};
            accNX[mt] = (f32x4){0.f, 0.f, 0.f, 0.f};
            accNH[mt] = (f32x4){0.f, 0.f, 0.f, 0.f};
        }

#pragma unroll
        for (int mt = 0; mt < 4; mt++) {
            const int seq = mt * 16 + lr;
            // xt A-frags built in-lane (no LDS): xt[seq][k] = relu(a*gW[k]+gb[k])
            short8 ax0, ax1;
#pragma unroll
            for (int j = 0; j < 8; j++) {
                ax0[j] = f2bf(fmaxf(fmaf(a_[mt], gw8[0][j], gb8[0][j]), 0.0f));
                ax1[j] = f2bf(fmaxf(fmaf(a_[mt], gw8[1][j], gb8[1][j]), 0.0f));
            }
            // h A-frags from swizzled LDS (b128, conflict-free per 8-lane group)
            const int s3 = seq & 7;
            short8 ah0 = *(const short8*)&hlds[seq * 64 + (((0 + qu) ^ s3) << 3)];
            short8 ah1 = *(const short8*)&hlds[seq * 64 + (((4 + qu) ^ s3) << 3)];

            accR[mt]  = __builtin_amdgcn_mfma_f32_16x16x32_bf16(ax0, bIr[0], accR[mt], 0, 0, 0);
            accR[mt]  = __builtin_amdgcn_mfma_f32_16x16x32_bf16(ax1, bIr[1], accR[mt], 0, 0, 0);
            accR[mt]  = __builtin_amdgcn_mfma_f32_16x16x32_bf16(ah0, bHr[0], accR[mt], 0, 0, 0);
            accR[mt]  = __builtin_amdgcn_mfma_f32_16x16x32_bf16(ah1, bHr[1], accR[mt], 0, 0, 0);
            accZ[mt]  = __builtin_amdgcn_mfma_f32_16x16x32_bf16(ax0, bIz[0], accZ[mt], 0, 0, 0);
            accZ[mt]  = __builtin_amdgcn_mfma_f32_16x16x32_bf16(ax1, bIz[1], accZ[mt], 0, 0, 0);
            accZ[mt]  = __builtin_amdgcn_mfma_f32_16x16x32_bf16(ah0, bHz[0], accZ[mt], 0, 0, 0);
            accZ[mt]  = __builtin_amdgcn_mfma_f32_16x16x32_bf16(ah1, bHz[1], accZ[mt], 0, 0, 0);
            accNX[mt] = __builtin_amdgcn_mfma_f32_16x16x32_bf16(ax0, bIn[0], accNX[mt], 0, 0, 0);
            accNX[mt] = __builtin_amdgcn_mfma_f32_16x16x32_bf16(ax1, bIn[1], accNX[mt], 0, 0, 0);
            accNH[mt] = __builtin_amdgcn_mfma_f32_16x16x32_bf16(ah0, bHn[0], accNH[mt], 0, 0, 0);
            accNH[mt] = __builtin_amdgcn_mfma_f32_16x16x32_bf16(ah1, bHn[1], accNH[mt], 0, 0, 0);
        }
        __syncthreads();   // all waves' h_{t-1} A-frag reads complete

        // elementwise gates in-register (C-layout: seq = mt*16 + qu*4 + r, col = u)
#pragma unroll
        for (int mt = 0; mt < 4; mt++) {
#pragma unroll
            for (int r = 0; r < 4; r++) {
                const int seq = mt * 16 + qu * 4 + r;
                float pr = sigmoid_f(accR[mt][r] + bR);
                float pz = sigmoid_f(accZ[mt][r] + bZ);
                float pn = tanh_f(fmaf(pr, accNH[mt][r] + bHN, accNX[mt][r] + bIN));
                float hn = fmaf(pz, h_c[mt][r] - pn, pn);   // (1-z)n + z h
                h_c[mt][r] = hn;
                hlds[seq * 64 + ((uc ^ (seq & 7)) << 3) + u7] = f2bf(hn);
            }
        }
        __syncthreads();   // h_t visible before next-t reads
    }

    // ---- output head: pred = h @ Wout^T + bout, one M-tile per wave ----
    short8 bWo[2];
#pragma unroll
    for (int kt = 0; kt < 2; kt++)
        bWo[kt] = *(const short8*)&Woutb[lr * 64 + kt * 32 + qu * 8];
    const float bo = (lr < P_OUT) ? bout[lr] : 0.0f;

    f32x4 accO = (f32x4){0.f, 0.f, 0.f, 0.f};
    {
        const int seq = w * 16 + lr;
        const int s3 = seq & 7;
        short8 ah0 = *(const short8*)&hlds[seq * 64 + (((0 + qu) ^ s3) << 3)];
        short8 ah1 = *(const short8*)&hlds[seq * 64 + (((4 + qu) ^ s3) << 3)];
        accO = __builtin_amdgcn_mfma_f32_16x16x32_bf16(ah0, bWo[0], accO, 0, 0, 0);
        accO = __builtin_amdgcn_mfma_f32_16x16x32_bf16(ah1, bWo[1], accO, 0, 0, 0);
    }
    if (lr < P_OUT) {
#pragma unroll
        for (int r = 0; r < 4; r++) {
            const int seq = w * 16 + qu * 4 + r;
            out[(blk * 64 + seq) * P_OUT + lr] = accO[r] + bo;
        }
    }
}

// ---------------- launcher ----------------

extern "C" void kernel_launch(void* const* d_in, const int* in_sizes, int n_in,
                              void* d_out, int out_size, void* d_ws, size_t ws_size,
                              hipStream_t stream)
{
    const float* x    = (const float*)d_in[0];
    const int*   ei   = (const int*)  d_in[1];
    const float* ew   = (const float*)d_in[2];
    const float* gW   = (const float*)d_in[3];
    const float* gb   = (const float*)d_in[4];
    const float* Wih  = (const float*)d_in[5];
    const float* Whh  = (const float*)d_in[6];
    const float* bih  = (const float*)d_in[7];
    const float* bhh  = (const float*)d_in[8];
    const float* Wout = (const float*)d_in[9];
    const float* bout = (const float*)d_in[10];
    float* out = (float*)d_out;

    float* deg   = (float*)d_ws;               // N floats (becomes dinv in-place)
    float* aggS  = deg + N_NODES;              // BN*T floats
    short* Wihb  = (short*)(aggS + BN * T_STEPS);   // 192*64 bf16
    short* Whhb  = Wihb + 192 * 64;
    short* Woutb = Whhb + 192 * 64;            // 16*64 bf16 (padded)

    hipMemsetAsync(deg, 0, N_NODES * sizeof(float), stream);
    cvt_kernel<<<48, 256, 0, stream>>>(Wih, Whh, Wout, Wihb, Whhb, Woutb);
    deg_kernel<<<(E_EDGES + 255) / 256, 256, 0, stream>>>(ei, ew, deg);
    dinv_kernel<<<(N_NODES + 255) / 256, 256, 0, stream>>>(deg);
    self_kernel<<<(BN * T_STEPS + 255) / 256, 256, 0, stream>>>(x, deg, aggS);
    edge_kernel<<<(E_EDGES * B + 255) / 256, 256, 0, stream>>>(ei, ew, deg, x, aggS);
    gru_mfma_kernel<<<BN / 64, 256, 0, stream>>>(aggS, gW, gb, Wihb, Whhb,
                                                 bih, bhh, Woutb, bout, out);
}

// Round 5
// 278.247 us; speedup vs baseline: 13.1548x; 3.4589x over previous
//
#include <hip/hip_runtime.h>

#define N_NODES 10000
#define B 8
#define T_STEPS 12
#define E_EDGES 160000
#define HG 64
#define HR 64
#define P_OUT 12
#define BN (B * N_NODES)   // 80000

typedef __attribute__((ext_vector_type(8))) short short8;
typedef __attribute__((ext_vector_type(4))) float f32x4;

__device__ __forceinline__ short f2bf(float f) {
    unsigned u = __builtin_bit_cast(unsigned, f);
    u += 0x7FFFu + ((u >> 16) & 1u);     // round-to-nearest-even
    return (short)(u >> 16);
}

// ---------------- GCN: degree + histogram ----------------
// deg[d] += ew[e]; cnt[d] += 1.  320k small atomics (vs 15.36M before).

__global__ void deg_hist_kernel(const int* __restrict__ ei, const float* __restrict__ ew,
                                float* __restrict__ deg, int* __restrict__ cnt) {
    int e = blockIdx.x * blockDim.x + threadIdx.x;
    if (e < E_EDGES) {
        int d = ei[E_EDGES + e];
        atomicAdd(&deg[d], ew[e]);
        atomicAdd(&cnt[d], 1);
    }
}

__global__ void dinv_kernel(float* __restrict__ deg) {
    int n = blockIdx.x * blockDim.x + threadIdx.x;
    if (n < N_NODES) deg[n] = rsqrtf(deg[n] + 1.0f);   // +1 = self-loop weight
}

// Single-block exclusive scan over cnt[0..N): off[n] = sum_{m<n} cnt[m].
// 256 threads x 40-element sequential chunks + Hillis-Steele over partials.
__global__ void scan_kernel(const int* __restrict__ cnt, int* __restrict__ off) {
    __shared__ int part[256];
    const int t = threadIdx.x;
    const int base = t * 40;               // 256*40 = 10240 >= N
    int s = 0;
#pragma unroll 1
    for (int i = 0; i < 40; i++) { int idx = base + i; if (idx < N_NODES) s += cnt[idx]; }
    part[t] = s; __syncthreads();
    for (int d = 1; d < 256; d <<= 1) {
        int v = (t >= d) ? part[t - d] : 0;
        __syncthreads();
        part[t] += v;
        __syncthreads();
    }
    int run = (t == 0) ? 0 : part[t - 1];
#pragma unroll 1
    for (int i = 0; i < 40; i++) {
        int idx = base + i;
        if (idx < N_NODES) { off[idx] = run; run += cnt[idx]; }
    }
}

// Fill CSR: pos = off[dst] + cursor[dst]++; store src + normalized edge weight.
__global__ void fill_kernel(const int* __restrict__ ei, const float* __restrict__ ew,
                            const float* __restrict__ dinv, const int* __restrict__ off,
                            int* __restrict__ cursor,
                            int* __restrict__ csr_src, float* __restrict__ csr_norm) {
    int e = blockIdx.x * blockDim.x + threadIdx.x;
    if (e >= E_EDGES) return;
    int s = ei[e];
    int d = ei[E_EDGES + e];
    int pos = off[d] + atomicAdd(&cursor[d], 1);
    csr_src[pos] = s;
    csr_norm[pos] = dinv[s] * ew[e] * dinv[d];
}

// Gather: one thread per (b,n) [tid = b*N + n -> writes coalesced, CSR reads
// near-sequential across lanes]. Self-loop folded into init. No atomics.
__global__ void gather_kernel(const float* __restrict__ x, const float* __restrict__ dinv,
                              const int* __restrict__ off, const int* __restrict__ cnt,
                              const int* __restrict__ csr_src, const float* __restrict__ csr_norm,
                              float* __restrict__ aggS) {
    int tid = blockIdx.x * blockDim.x + threadIdx.x;
    if (tid >= BN) return;
    int n = tid % N_NODES;
    int b = tid / N_NODES;
    float di = dinv[n];
    float acc[T_STEPS];
    {
        const float4* xp = reinterpret_cast<const float4*>(&x[(b * N_NODES + n) * T_STEPS]);
        float4 x0 = xp[0], x1 = xp[1], x2 = xp[2];
        float w = di * di;
        acc[0] = w * x0.x; acc[1] = w * x0.y; acc[2]  = w * x0.z; acc[3]  = w * x0.w;
        acc[4] = w * x1.x; acc[5] = w * x1.y; acc[6]  = w * x1.z; acc[7]  = w * x1.w;
        acc[8] = w * x2.x; acc[9] = w * x2.y; acc[10] = w * x2.z; acc[11] = w * x2.w;
    }
    const int o0 = off[n], c = cnt[n];
#pragma unroll 1
    for (int i = 0; i < c; i++) {
        int s = csr_src[o0 + i];
        float w = csr_norm[o0 + i];
        const float4* xp = reinterpret_cast<const float4*>(&x[(b * N_NODES + s) * T_STEPS]);
        float4 x0 = xp[0], x1 = xp[1], x2 = xp[2];
        acc[0]  = fmaf(w, x0.x, acc[0]);  acc[1]  = fmaf(w, x0.y, acc[1]);
        acc[2]  = fmaf(w, x0.z, acc[2]);  acc[3]  = fmaf(w, x0.w, acc[3]);
        acc[4]  = fmaf(w, x1.x, acc[4]);  acc[5]  = fmaf(w, x1.y, acc[5]);
        acc[6]  = fmaf(w, x1.z, acc[6]);  acc[7]  = fmaf(w, x1.w, acc[7]);
        acc[8]  = fmaf(w, x2.x, acc[8]);  acc[9]  = fmaf(w, x2.y, acc[9]);
        acc[10] = fmaf(w, x2.z, acc[10]); acc[11] = fmaf(w, x2.w, acc[11]);
    }
#pragma unroll
    for (int t = 0; t < T_STEPS; t++) aggS[t * BN + tid] = acc[t];
}

// ---------------- weight conversion to bf16 ----------------

__global__ void cvt_kernel(const float* __restrict__ Wih, const float* __restrict__ Whh,
                           const float* __restrict__ Wout,
                           short* __restrict__ Wihb, short* __restrict__ Whhb,
                           short* __restrict__ Woutb) {
    int i = blockIdx.x * blockDim.x + threadIdx.x;
    if (i < 192 * 64) {
        Wihb[i] = f2bf(Wih[i]);
        Whhb[i] = f2bf(Whh[i]);
    }
    if (i < 16 * 64) {
        int p = i >> 6, k = i & 63;
        Woutb[i] = (p < P_OUT) ? f2bf(Wout[p * 64 + k]) : (short)0;
    }
}

// ---------------- Fused MFMA GRU + output head ----------------

__device__ __forceinline__ float fast_rcp(float v) { return __builtin_amdgcn_rcpf(v); }
__device__ __forceinline__ float sigmoid_f(float v) { return fast_rcp(1.0f + __expf(-v)); }
__device__ __forceinline__ float tanh_f(float v) {
    float e = __expf(-2.0f * v);
    return fmaf(2.0f, fast_rcp(1.0f + e), -1.0f);
}

// Block = 64 sequences, 4 waves. Wave w owns gate-units u in [16w,16w+16).
// Per t: gates(64 x 192) = X(64x64)*Wih^T + H(64x64)*Whh^T via 16x16x32 bf16
// MFMA. Four acc sets (r,z,n_x,n_h) share tile coords -> elementwise is pure
// in-register. h: fp32 C-layout regs + bf16 XOR-swizzled LDS copy for A-frags.
// Weights pinned in B-frag registers for the whole kernel.
__global__ __launch_bounds__(256, 2) void gru_mfma_kernel(
    const float* __restrict__ aggS,
    const float* __restrict__ gW, const float* __restrict__ gb,
    const short* __restrict__ Wihb, const short* __restrict__ Whhb,
    const float* __restrict__ bih, const float* __restrict__ bhh,
    const short* __restrict__ Woutb, const float* __restrict__ bout,
    float* __restrict__ out)
{
    __shared__ short hlds[64 * 64];   // 8 KB
    const int tid = threadIdx.x;
    const int w   = tid >> 6;
    const int l   = tid & 63;
    const int lr  = l & 15;
    const int qu  = l >> 4;
    const int blk = blockIdx.x;

    short8 bIr[2], bIz[2], bIn[2], bHr[2], bHz[2], bHn[2];
#pragma unroll
    for (int kt = 0; kt < 2; kt++) {
        const int ko = kt * 32 + qu * 8;
        bIr[kt] = *(const short8*)&Wihb[(      16 * w + lr) * 64 + ko];
        bIz[kt] = *(const short8*)&Wihb[( 64 + 16 * w + lr) * 64 + ko];
        bIn[kt] = *(const short8*)&Wihb[(128 + 16 * w + lr) * 64 + ko];
        bHr[kt] = *(const short8*)&Whhb[(      16 * w + lr) * 64 + ko];
        bHz[kt] = *(const short8*)&Whhb[( 64 + 16 * w + lr) * 64 + ko];
        bHn[kt] = *(const short8*)&Whhb[(128 + 16 * w + lr) * 64 + ko];
    }
    float gw8[2][8], gb8[2][8];
#pragma unroll
    for (int kt = 0; kt < 2; kt++) {
        const int ko = kt * 32 + qu * 8;
#pragma unroll
        for (int j = 0; j < 8; j++) { gw8[kt][j] = gW[ko + j]; gb8[kt][j] = gb[ko + j]; }
    }
    const int u = 16 * w + lr;
    const float bR  = bih[u]       + bhh[u];
    const float bZ  = bih[u + 64]  + bhh[u + 64];
    const float bIN = bih[u + 128];
    const float bHN = bhh[u + 128];
    const int uc = u >> 3;
    const int u7 = u & 7;

    float h_c[4][4];
#pragma unroll
    for (int mt = 0; mt < 4; mt++)
#pragma unroll
        for (int r = 0; r < 4; r++) h_c[mt][r] = 0.0f;
#pragma unroll
    for (int i = 0; i < 16; i++) hlds[tid * 16 + i] = 0;
    __syncthreads();

#pragma unroll 1
    for (int t = 0; t < T_STEPS; t++) {
        float a_[4];
#pragma unroll
        for (int mt = 0; mt < 4; mt++)
            a_[mt] = aggS[t * BN + blk * 64 + mt * 16 + lr];

        f32x4 accR[4], accZ[4], accNX[4], accNH[4];
#pragma unroll
        for (int mt = 0; mt < 4; mt++) {
            accR[mt]  = (f32x4){0.f, 0.f, 0.f, 0.f};
            accZ[mt]  = (f32x4){0.f, 0.f, 0.f, 0.f};
            accNX[mt] = (f32x4){0.f, 0.f, 0.f, 0.f};
            accNH[mt] = (f32x4){0.f, 0.f, 0.f, 0.f};
        }

#pragma unroll
        for (int mt = 0; mt < 4; mt++) {
            const int seq = mt * 16 + lr;
            short8 ax0, ax1;
#pragma unroll
            for (int j = 0; j < 8; j++) {
                ax0[j] = f2bf(fmaxf(fmaf(a_[mt], gw8[0][j], gb8[0][j]), 0.0f));
                ax1[j] = f2bf(fmaxf(fmaf(a_[mt], gw8[1][j], gb8[1][j]), 0.0f));
            }
            const int s3 = seq & 7;
            short8 ah0 = *(const short8*)&hlds[seq * 64 + (((0 + qu) ^ s3) << 3)];
            short8 ah1 = *(const short8*)&hlds[seq * 64 + (((4 + qu) ^ s3) << 3)];

            accR[mt]  = __builtin_amdgcn_mfma_f32_16x16x32_bf16(ax0, bIr[0], accR[mt], 0, 0, 0);
            accR[mt]  = __builtin_amdgcn_mfma_f32_16x16x32_bf16(ax1, bIr[1], accR[mt], 0, 0, 0);
            accR[mt]  = __builtin_amdgcn_mfma_f32_16x16x32_bf16(ah0, bHr[0], accR[mt], 0, 0, 0);
            accR[mt]  = __builtin_amdgcn_mfma_f32_16x16x32_bf16(ah1, bHr[1], accR[mt], 0, 0, 0);
            accZ[mt]  = __builtin_amdgcn_mfma_f32_16x16x32_bf16(ax0, bIz[0], accZ[mt], 0, 0, 0);
            accZ[mt]  = __builtin_amdgcn_mfma_f32_16x16x32_bf16(ax1, bIz[1], accZ[mt], 0, 0, 0);
            accZ[mt]  = __builtin_amdgcn_mfma_f32_16x16x32_bf16(ah0, bHz[0], accZ[mt], 0, 0, 0);
            accZ[mt]  = __builtin_amdgcn_mfma_f32_16x16x32_bf16(ah1, bHz[1], accZ[mt], 0, 0, 0);
            accNX[mt] = __builtin_amdgcn_mfma_f32_16x16x32_bf16(ax0, bIn[0], accNX[mt], 0, 0, 0);
            accNX[mt] = __builtin_amdgcn_mfma_f32_16x16x32_bf16(ax1, bIn[1], accNX[mt], 0, 0, 0);
            accNH[mt] = __builtin_amdgcn_mfma_f32_16x16x32_bf16(ah0, bHn[0], accNH[mt], 0, 0, 0);
            accNH[mt] = __builtin_amdgcn_mfma_f32_16x16x32_bf16(ah1, bHn[1], accNH[mt], 0, 0, 0);
        }
        __syncthreads();

#pragma unroll
        for (int mt = 0; mt < 4; mt++) {
#pragma unroll
            for (int r = 0; r < 4; r++) {
                const int seq = mt * 16 + qu * 4 + r;
                float pr = sigmoid_f(accR[mt][r] + bR);
                float pz = sigmoid_f(accZ[mt][r] + bZ);
                float pn = tanh_f(fmaf(pr, accNH[mt][r] + bHN, accNX[mt][r] + bIN));
                float hn = fmaf(pz, h_c[mt][r] - pn, pn);
                h_c[mt][r] = hn;
                hlds[seq * 64 + ((uc ^ (seq & 7)) << 3) + u7] = f2bf(hn);
            }
        }
        __syncthreads();
    }

    short8 bWo[2];
#pragma unroll
    for (int kt = 0; kt < 2; kt++)
        bWo[kt] = *(const short8*)&Woutb[lr * 64 + kt * 32 + qu * 8];
    const float bo = (lr < P_OUT) ? bout[lr] : 0.0f;

    f32x4 accO = (f32x4){0.f, 0.f, 0.f, 0.f};
    {
        const int seq = w * 16 + lr;
        const int s3 = seq & 7;
        short8 ah0 = *(const short8*)&hlds[seq * 64 + (((0 + qu) ^ s3) << 3)];
        short8 ah1 = *(const short8*)&hlds[seq * 64 + (((4 + qu) ^ s3) << 3)];
        accO = __builtin_amdgcn_mfma_f32_16x16x32_bf16(ah0, bWo[0], accO, 0, 0, 0);
        accO = __builtin_amdgcn_mfma_f32_16x16x32_bf16(ah1, bWo[1], accO, 0, 0, 0);
    }
    if (lr < P_OUT) {
#pragma unroll
        for (int r = 0; r < 4; r++) {
            const int seq = w * 16 + qu * 4 + r;
            out[(blk * 64 + seq) * P_OUT + lr] = accO[r] + bo;
        }
    }
}

// ---------------- launcher ----------------

extern "C" void kernel_launch(void* const* d_in, const int* in_sizes, int n_in,
                              void* d_out, int out_size, void* d_ws, size_t ws_size,
                              hipStream_t stream)
{
    const float* x    = (const float*)d_in[0];
    const int*   ei   = (const int*)  d_in[1];
    const float* ew   = (const float*)d_in[2];
    const float* gW   = (const float*)d_in[3];
    const float* gb   = (const float*)d_in[4];
    const float* Wih  = (const float*)d_in[5];
    const float* Whh  = (const float*)d_in[6];
    const float* bih  = (const float*)d_in[7];
    const float* bhh  = (const float*)d_in[8];
    const float* Wout = (const float*)d_in[9];
    const float* bout = (const float*)d_in[10];
    float* out = (float*)d_out;

    // workspace layout (all 4B types first, bf16 weights at the end; offsets 16B-aligned)
    float* deg      = (float*)d_ws;                 // N
    int*   cnt      = (int*)(deg + N_NODES);        // N
    int*   cursor   = cnt + N_NODES;                // N
    int*   off      = cursor + N_NODES;             // N
    int*   csr_src  = off + N_NODES;                // E
    float* csr_norm = (float*)(csr_src + E_EDGES);  // E
    float* aggS     = csr_norm + E_EDGES;           // BN*T
    short* Wihb     = (short*)(aggS + BN * T_STEPS);
    short* Whhb     = Wihb + 192 * 64;
    short* Woutb    = Whhb + 192 * 64;

    // one memset covers deg + cnt + cursor (contiguous)
    hipMemsetAsync(deg, 0, 3 * N_NODES * sizeof(float), stream);
    cvt_kernel<<<48, 256, 0, stream>>>(Wih, Whh, Wout, Wihb, Whhb, Woutb);
    deg_hist_kernel<<<(E_EDGES + 255) / 256, 256, 0, stream>>>(ei, ew, deg, cnt);
    dinv_kernel<<<(N_NODES + 255) / 256, 256, 0, stream>>>(deg);
    scan_kernel<<<1, 256, 0, stream>>>(cnt, off);
    fill_kernel<<<(E_EDGES + 255) / 256, 256, 0, stream>>>(ei, ew, deg, off, cursor,
                                                           csr_src, csr_norm);
    gather_kernel<<<(BN + 255) / 256, 256, 0, stream>>>(x, deg, off, cnt,
                                                        csr_src, csr_norm, aggS);
    gru_mfma_kernel<<<BN / 64, 256, 0, stream>>>(aggS, gW, gb, Wihb, Whhb,
                                                 bih, bhh, Woutb, bout, out);
}

// Round 6
// 241.408 us; speedup vs baseline: 15.1622x; 1.1526x over previous
//
#include <hip/hip_runtime.h>

#define N_NODES 10000
#define B 8
#define T_STEPS 12
#define E_EDGES 160000
#define HG 64
#define HR 64
#define P_OUT 12
#define BN (B * N_NODES)   // 80000

typedef __attribute__((ext_vector_type(8))) short short8;
typedef __attribute__((ext_vector_type(4))) float f32x4;

__device__ __forceinline__ short f2bf(float f) {
    unsigned u = __builtin_bit_cast(unsigned, f);
    u += 0x7FFFu + ((u >> 16) & 1u);     // round-to-nearest-even
    return (short)(u >> 16);
}

// ---------------- prep: deg/cnt histogram + weight cvt (fused) ----------------
// blocks [0,625): one thread per edge -> deg/cnt atomics.
// blocks [625,673): weight bf16 conversion (12288 threads).

__global__ void prep_kernel(const int* __restrict__ ei, const float* __restrict__ ew,
                            float* __restrict__ deg, int* __restrict__ cnt,
                            const float* __restrict__ Wih, const float* __restrict__ Whh,
                            const float* __restrict__ Wout,
                            short* __restrict__ Wihb, short* __restrict__ Whhb,
                            short* __restrict__ Woutb) {
    if (blockIdx.x < 625) {
        int e = blockIdx.x * 256 + threadIdx.x;          // 625*256 == E_EDGES
        int d = ei[E_EDGES + e];
        atomicAdd(&deg[d], ew[e]);
        atomicAdd(&cnt[d], 1);
    } else {
        int i = (blockIdx.x - 625) * 256 + threadIdx.x;
        if (i < 192 * 64) {
            Wihb[i] = f2bf(Wih[i]);
            Whhb[i] = f2bf(Whh[i]);
        }
        if (i < 16 * 64) {
            int p = i >> 6, k = i & 63;
            Woutb[i] = (p < P_OUT) ? f2bf(Wout[p * 64 + k]) : (short)0;
        }
    }
}

// ---------------- scan (exclusive) + dinv, single block ----------------
// Coalesced global<->LDS staging; 16-way LDS conflict in the per-thread chunk
// sum is ~0.5us total, irrelevant.
__global__ void scan_dinv_kernel(const int* __restrict__ cnt, int* __restrict__ off,
                                 float* __restrict__ deg) {
    __shared__ int buf[10240];   // 40 KB
    __shared__ int part[256];
    const int t = threadIdx.x;
#pragma unroll 1
    for (int i = 0; i < 40; i++) {
        int idx = i * 256 + t;
        buf[idx] = (idx < N_NODES) ? cnt[idx] : 0;
    }
    __syncthreads();
    int s = 0;
#pragma unroll 1
    for (int i = 0; i < 40; i++) s += buf[t * 40 + i];
    part[t] = s;
    __syncthreads();
    for (int d = 1; d < 256; d <<= 1) {
        int v = (t >= d) ? part[t - d] : 0;
        __syncthreads();
        part[t] += v;
        __syncthreads();
    }
    int run = (t == 0) ? 0 : part[t - 1];
#pragma unroll 1
    for (int i = 0; i < 40; i++) {
        int idx = t * 40 + i;
        int c = buf[idx];
        buf[idx] = run;
        run += c;
    }
    __syncthreads();
#pragma unroll 1
    for (int i = 0; i < 40; i++) {
        int idx = i * 256 + t;
        if (idx < N_NODES) {
            off[idx] = buf[idx];
            deg[idx] = rsqrtf(deg[idx] + 1.0f);   // deg -> dinv in place
        }
    }
}

// ---------------- fill CSR (interleaved int2: src, norm-bits) ----------------
__global__ void fill_kernel(const int* __restrict__ ei, const float* __restrict__ ew,
                            const float* __restrict__ dinv, const int* __restrict__ off,
                            int* __restrict__ cursor, int2* __restrict__ csr) {
    int e = blockIdx.x * blockDim.x + threadIdx.x;
    if (e >= E_EDGES) return;
    int s = ei[e];
    int d = ei[E_EDGES + e];
    int pos = off[d] + atomicAdd(&cursor[d], 1);
    csr[pos] = make_int2(s, __float_as_int(dinv[s] * ew[e] * dinv[d]));
}

// ---------------- gather (CSR, no atomics), aggS layout [bn][12] ----------------
__global__ void gather_kernel(const float* __restrict__ x, const float* __restrict__ dinv,
                              const int* __restrict__ off, const int* __restrict__ cnt,
                              const int2* __restrict__ csr, float* __restrict__ aggS) {
    int tid = blockIdx.x * blockDim.x + threadIdx.x;
    if (tid >= BN) return;
    int n = tid % N_NODES;
    int b = tid / N_NODES;
    float di = dinv[n];
    float acc[T_STEPS];
    {
        const float4* xp = reinterpret_cast<const float4*>(&x[(b * N_NODES + n) * T_STEPS]);
        float4 x0 = xp[0], x1 = xp[1], x2 = xp[2];
        float w = di * di;
        acc[0] = w * x0.x; acc[1] = w * x0.y; acc[2]  = w * x0.z; acc[3]  = w * x0.w;
        acc[4] = w * x1.x; acc[5] = w * x1.y; acc[6]  = w * x1.z; acc[7]  = w * x1.w;
        acc[8] = w * x2.x; acc[9] = w * x2.y; acc[10] = w * x2.z; acc[11] = w * x2.w;
    }
    const int o0 = off[n], c = cnt[n];
    const int2* cp = &csr[o0];
#pragma unroll 2
    for (int i = 0; i < c; i++) {
        int2 pr = cp[i];
        float w = __int_as_float(pr.y);
        const float4* xp = reinterpret_cast<const float4*>(&x[(b * N_NODES + pr.x) * T_STEPS]);
        float4 x0 = xp[0], x1 = xp[1], x2 = xp[2];
        acc[0]  = fmaf(w, x0.x, acc[0]);  acc[1]  = fmaf(w, x0.y, acc[1]);
        acc[2]  = fmaf(w, x0.z, acc[2]);  acc[3]  = fmaf(w, x0.w, acc[3]);
        acc[4]  = fmaf(w, x1.x, acc[4]);  acc[5]  = fmaf(w, x1.y, acc[5]);
        acc[6]  = fmaf(w, x1.z, acc[6]);  acc[7]  = fmaf(w, x1.w, acc[7]);
        acc[8]  = fmaf(w, x2.x, acc[8]);  acc[9]  = fmaf(w, x2.y, acc[9]);
        acc[10] = fmaf(w, x2.z, acc[10]); acc[11] = fmaf(w, x2.w, acc[11]);
    }
    float4* ap = reinterpret_cast<float4*>(&aggS[tid * T_STEPS]);   // 48B-aligned
    ap[0] = make_float4(acc[0], acc[1], acc[2],  acc[3]);
    ap[1] = make_float4(acc[4], acc[5], acc[6],  acc[7]);
    ap[2] = make_float4(acc[8], acc[9], acc[10], acc[11]);
}

// ---------------- Fused MFMA GRU + output head ----------------

__device__ __forceinline__ float fast_rcp(float v) { return __builtin_amdgcn_rcpf(v); }
__device__ __forceinline__ float sigmoid_f(float v) { return fast_rcp(1.0f + __expf(-v)); }
__device__ __forceinline__ float tanh_f(float v) {
    float e = __expf(-2.0f * v);
    return fmaf(2.0f, fast_rcp(1.0f + e), -1.0f);
}

// Block = 64 sequences, 4 waves; wave w owns gate-units [16w,16w+16).
// New vs R5: (1) X-tile computed ONCE per block into xlds (each thread 16
// cvt-chains, not 64; read back as b128 A-frags), (2) all 12 aggS scalars
// preloaded as 3x float4, (3) gate biases folded into acc init.
__global__ __launch_bounds__(256, 2) void gru_mfma_kernel(
    const float* __restrict__ aggS,
    const float* __restrict__ gW, const float* __restrict__ gb,
    const short* __restrict__ Wihb, const short* __restrict__ Whhb,
    const float* __restrict__ bih, const float* __restrict__ bhh,
    const short* __restrict__ Woutb, const float* __restrict__ bout,
    float* __restrict__ out)
{
    __shared__ short hlds[64 * 64];   // 8 KB, row=seq, chunk c at slot (c ^ (seq&7))
    __shared__ short xlds[64 * 64];   // 8 KB, same swizzle
    const int tid = threadIdx.x;
    const int w   = tid >> 6;
    const int wu  = __builtin_amdgcn_readfirstlane(w);   // force wave-uniform (SGPR)
    const int l   = tid & 63;
    const int lr  = l & 15;
    const int qu  = l >> 4;
    const int blk = blockIdx.x;

    // t-invariant weight B-frags (pinned in registers)
    short8 bIr[2], bIz[2], bIn[2], bHr[2], bHz[2], bHn[2];
#pragma unroll
    for (int kt = 0; kt < 2; kt++) {
        const int ko = kt * 32 + qu * 8;
        bIr[kt] = *(const short8*)&Wihb[(      16 * wu + lr) * 64 + ko];
        bIz[kt] = *(const short8*)&Wihb[( 64 + 16 * wu + lr) * 64 + ko];
        bIn[kt] = *(const short8*)&Wihb[(128 + 16 * wu + lr) * 64 + ko];
        bHr[kt] = *(const short8*)&Whhb[(      16 * wu + lr) * 64 + ko];
        bHz[kt] = *(const short8*)&Whhb[( 64 + 16 * wu + lr) * 64 + ko];
        bHn[kt] = *(const short8*)&Whhb[(128 + 16 * wu + lr) * 64 + ko];
    }
    // X-stage constants: this wave covers k in [16wu, 16wu+16) -> scalar loads
    float gwv[16], gbv[16];
#pragma unroll
    for (int j = 0; j < 16; j++) { gwv[j] = gW[wu * 16 + j]; gbv[j] = gb[wu * 16 + j]; }

    const int u = 16 * w + lr;
    const float bR  = bih[u]       + bhh[u];
    const float bZ  = bih[u + 64]  + bhh[u + 64];
    const float bIN = bih[u + 128];
    const float bHN = bhh[u + 128];
    const int uc = u >> 3;
    const int u7 = u & 7;

    // all 12 aggS scalars for seq=l (aggS layout [bn][12], 48B/seq)
    float a_all[12];
    {
        const float4* ap = reinterpret_cast<const float4*>(&aggS[(blk * 64 + l) * T_STEPS]);
        float4 a0 = ap[0], a1 = ap[1], a2 = ap[2];
        a_all[0] = a0.x; a_all[1] = a0.y; a_all[2]  = a0.z; a_all[3]  = a0.w;
        a_all[4] = a1.x; a_all[5] = a1.y; a_all[6]  = a1.z; a_all[7]  = a1.w;
        a_all[8] = a2.x; a_all[9] = a2.y; a_all[10] = a2.z; a_all[11] = a2.w;
    }

    float h_c[4][4];
#pragma unroll
    for (int mt = 0; mt < 4; mt++)
#pragma unroll
        for (int r = 0; r < 4; r++) h_c[mt][r] = 0.0f;
    // zero h LDS (2 b128 stores/thread)
    {
        short8 z = (short8){0,0,0,0,0,0,0,0};
        *(short8*)&hlds[l * 64 + ((2 * w) << 3)]     = z;
        *(short8*)&hlds[l * 64 + ((2 * w + 1) << 3)] = z;
    }

#pragma unroll 1
    for (int t = 0; t < T_STEPS; t++) {
        // ---- X-stage: seq=l, k in [16wu,16wu+16), chunks 2w/2w+1, swizzled
        {
            const float a = a_all[t];
            short8 c0, c1;
#pragma unroll
            for (int j = 0; j < 8; j++) {
                c0[j] = f2bf(fmaxf(fmaf(a, gwv[j],     gbv[j]),     0.0f));
                c1[j] = f2bf(fmaxf(fmaf(a, gwv[8 + j], gbv[8 + j]), 0.0f));
            }
            const int s3 = l & 7;
            *(short8*)&xlds[l * 64 + (((2 * w)     ^ s3) << 3)] = c0;
            *(short8*)&xlds[l * 64 + (((2 * w + 1) ^ s3) << 3)] = c1;
        }
        __syncthreads();   // X_t + h_{t-1} (prev iter) visible

        f32x4 accR[4], accZ[4], accNX[4], accNH[4];
#pragma unroll
        for (int mt = 0; mt < 4; mt++) {
            accR[mt]  = (f32x4){bR,  bR,  bR,  bR};
            accZ[mt]  = (f32x4){bZ,  bZ,  bZ,  bZ};
            accNX[mt] = (f32x4){bIN, bIN, bIN, bIN};
            accNH[mt] = (f32x4){bHN, bHN, bHN, bHN};
        }

#pragma unroll
        for (int mt = 0; mt < 4; mt++) {
            const int seq = mt * 16 + lr;
            const int s3 = seq & 7;
            short8 ax0 = *(const short8*)&xlds[seq * 64 + (((0 + qu) ^ s3) << 3)];
            short8 ax1 = *(const short8*)&xlds[seq * 64 + (((4 + qu) ^ s3) << 3)];
            short8 ah0 = *(const short8*)&hlds[seq * 64 + (((0 + qu) ^ s3) << 3)];
            short8 ah1 = *(const short8*)&hlds[seq * 64 + (((4 + qu) ^ s3) << 3)];

            accR[mt]  = __builtin_amdgcn_mfma_f32_16x16x32_bf16(ax0, bIr[0], accR[mt], 0, 0, 0);
            accR[mt]  = __builtin_amdgcn_mfma_f32_16x16x32_bf16(ax1, bIr[1], accR[mt], 0, 0, 0);
            accR[mt]  = __builtin_amdgcn_mfma_f32_16x16x32_bf16(ah0, bHr[0], accR[mt], 0, 0, 0);
            accR[mt]  = __builtin_amdgcn_mfma_f32_16x16x32_bf16(ah1, bHr[1], accR[mt], 0, 0, 0);
            accZ[mt]  = __builtin_amdgcn_mfma_f32_16x16x32_bf16(ax0, bIz[0], accZ[mt], 0, 0, 0);
            accZ[mt]  = __builtin_amdgcn_mfma_f32_16x16x32_bf16(ax1, bIz[1], accZ[mt], 0, 0, 0);
            accZ[mt]  = __builtin_amdgcn_mfma_f32_16x16x32_bf16(ah0, bHz[0], accZ[mt], 0, 0, 0);
            accZ[mt]  = __builtin_amdgcn_mfma_f32_16x16x32_bf16(ah1, bHz[1], accZ[mt], 0, 0, 0);
            accNX[mt] = __builtin_amdgcn_mfma_f32_16x16x32_bf16(ax0, bIn[0], accNX[mt], 0, 0, 0);
            accNX[mt] = __builtin_amdgcn_mfma_f32_16x16x32_bf16(ax1, bIn[1], accNX[mt], 0, 0, 0);
            accNH[mt] = __builtin_amdgcn_mfma_f32_16x16x32_bf16(ah0, bHn[0], accNH[mt], 0, 0, 0);
            accNH[mt] = __builtin_amdgcn_mfma_f32_16x16x32_bf16(ah1, bHn[1], accNH[mt], 0, 0, 0);
        }
        __syncthreads();   // all A-frag reads complete

#pragma unroll
        for (int mt = 0; mt < 4; mt++) {
#pragma unroll
            for (int r = 0; r < 4; r++) {
                const int seq = mt * 16 + qu * 4 + r;
                float pr = sigmoid_f(accR[mt][r]);
                float pz = sigmoid_f(accZ[mt][r]);
                float pn = tanh_f(fmaf(pr, accNH[mt][r], accNX[mt][r]));
                float hn = fmaf(pz, h_c[mt][r] - pn, pn);
                h_c[mt][r] = hn;
                hlds[seq * 64 + ((uc ^ (seq & 7)) << 3) + u7] = f2bf(hn);
            }
        }
    }
    __syncthreads();   // final h visible for head

    // ---- output head ----
    short8 bWo[2];
#pragma unroll
    for (int kt = 0; kt < 2; kt++)
        bWo[kt] = *(const short8*)&Woutb[lr * 64 + kt * 32 + qu * 8];
    const float bo = (lr < P_OUT) ? bout[lr] : 0.0f;

    f32x4 accO = (f32x4){0.f, 0.f, 0.f, 0.f};
    {
        const int seq = w * 16 + lr;
        const int s3 = seq & 7;
        short8 ah0 = *(const short8*)&hlds[seq * 64 + (((0 + qu) ^ s3) << 3)];
        short8 ah1 = *(const short8*)&hlds[seq * 64 + (((4 + qu) ^ s3) << 3)];
        accO = __builtin_amdgcn_mfma_f32_16x16x32_bf16(ah0, bWo[0], accO, 0, 0, 0);
        accO = __builtin_amdgcn_mfma_f32_16x16x32_bf16(ah1, bWo[1], accO, 0, 0, 0);
    }
    if (lr < P_OUT) {
#pragma unroll
        for (int r = 0; r < 4; r++) {
            const int seq = w * 16 + qu * 4 + r;
            out[(blk * 64 + seq) * P_OUT + lr] = accO[r] + bo;
        }
    }
}

// ---------------- launcher ----------------

extern "C" void kernel_launch(void* const* d_in, const int* in_sizes, int n_in,
                              void* d_out, int out_size, void* d_ws, size_t ws_size,
                              hipStream_t stream)
{
    const float* x    = (const float*)d_in[0];
    const int*   ei   = (const int*)  d_in[1];
    const float* ew   = (const float*)d_in[2];
    const float* gW   = (const float*)d_in[3];
    const float* gb   = (const float*)d_in[4];
    const float* Wih  = (const float*)d_in[5];
    const float* Whh  = (const float*)d_in[6];
    const float* bih  = (const float*)d_in[7];
    const float* bhh  = (const float*)d_in[8];
    const float* Wout = (const float*)d_in[9];
    const float* bout = (const float*)d_in[10];
    float* out = (float*)d_out;

    float* deg    = (float*)d_ws;                 // N
    int*   cnt    = (int*)(deg + N_NODES);        // N
    int*   cursor = cnt + N_NODES;                // N
    int*   off    = cursor + N_NODES;             // N
    int2*  csr    = (int2*)(off + N_NODES);       // E (8B each, offset 640000B: 8-aligned)
    float* aggS   = (float*)(csr + E_EDGES);      // BN*12, layout [bn][12]
    short* Wihb   = (short*)(aggS + BN * T_STEPS);
    short* Whhb   = Wihb + 192 * 64;
    short* Woutb  = Whhb + 192 * 64;

    hipMemsetAsync(deg, 0, 3 * N_NODES * sizeof(float), stream);   // deg+cnt+cursor
    prep_kernel<<<673, 256, 0, stream>>>(ei, ew, deg, cnt, Wih, Whh, Wout,
                                         Wihb, Whhb, Woutb);
    scan_dinv_kernel<<<1, 256, 0, stream>>>(cnt, off, deg);
    fill_kernel<<<(E_EDGES + 255) / 256, 256, 0, stream>>>(ei, ew, deg, off, cursor, csr);
    gather_kernel<<<(BN + 255) / 256, 256, 0, stream>>>(x, deg, off, cnt, csr, aggS);
    gru_mfma_kernel<<<BN / 64, 256, 0, stream>>>(aggS, gW, gb, Wihb, Whhb,
                                                 bih, bhh, Woutb, bout, out);
}